// Round 7
// baseline (224.503 us; speedup 1.0000x reference)
//
#include <hip/hip_runtime.h>
#include <math.h>

#define BATCH 8
#define FDIM  64
#define NDIM  2048
#define MTOT  (BATCH * FDIM * NDIM)
#define SIGMA 2.0f
#define LOG2E 1.4426950408889634f

#define COLSQ_N (BATCH * NDIM)             // 16384 colsq floats
#define NPREP   256                        // prep block count
#define PSUM_OFF (COLSQ_N)                 // 256 per-block sums
#define PSQ_OFF  (COLSQ_N + NPREP)         // 256 per-block sumsqs
#define EMBT_OFF (COLSQ_N + 2 * NPREP)     // bf16 embT starts (byte 67584, 64B aligned)

typedef __attribute__((ext_vector_type(8))) short bf16x8;
typedef __attribute__((ext_vector_type(4))) float f32x4;

static __device__ inline unsigned short f2bf(float x) {
    unsigned int u = __float_as_uint(x);
    return (unsigned short)((u + 0x7fffu + ((u >> 16) & 1u)) >> 16);   // RTNE
}

// prep: 256 blocks x 1 wave, one column per thread. Produces:
//   colsq[b*NDIM+n], per-block partial (sum,sumsq) — no atomics, no memset —
//   and bf16 embT[b][n][f] for 16B-coalesced GEMM fragment loads.
__global__ __launch_bounds__(64) void prep_kernel(
        const float* __restrict__ emb, float* __restrict__ ws) {
    const int blk = blockIdx.x;
    const int b = blk >> 5;
    const int n = ((blk & 31) << 6) + threadIdx.x;
    const float* p = emb + (size_t)b * FDIM * NDIM + n;
    unsigned short* dst = (unsigned short*)(ws + EMBT_OFF) + (size_t)(b * NDIM + n) * FDIM;

    float s = 0.f, q = 0.f;
#pragma unroll
    for (int f0 = 0; f0 < FDIM; f0 += 8) {
        unsigned int wv[4];
#pragma unroll
        for (int j = 0; j < 4; ++j) {
            float a = p[(size_t)(f0 + 2 * j) * NDIM];
            float c = p[(size_t)(f0 + 2 * j + 1) * NDIM];
            s += a + c;
            q += a * a + c * c;
            wv[j] = (unsigned)f2bf(a) | ((unsigned)f2bf(c) << 16);
        }
        *(uint4*)(dst + f0) = make_uint4(wv[0], wv[1], wv[2], wv[3]);
    }
    ws[b * NDIM + n] = q;

#pragma unroll
    for (int off = 32; off > 0; off >>= 1) {
        s += __shfl_down(s, off, 64);
        q += __shfl_down(q, off, 64);
    }
    if (threadIdx.x == 0) {
        ws[PSUM_OFF + blk] = s;
        ws[PSQ_OFF + blk] = q;
    }
}

// gauss v2 (R7): BARRIER-FREE, ZERO-LDS. embT is 2 MB (L2-resident), so the
// LDS staging round-trip bought 4x reuse on already-cached data while costing
// a staging phase + __syncthreads + 33 KB LDS (4 blocks/CU cap). Now:
//   - MFMA fragments load directly from global embT (same 16-row x 64B
//     gather the LDS reads had; L2 hits, no bank concept, no swizzle)
//   - the 256 prep partials reduce per-wave: 8 coalesced loads + shfl_xor
//     butterfly (all lanes get S,Q; no red[], no barrier)
//   - qnt/qm4 bias terms read straight from the L2-hot colsq array
// Waves are fully independent: no lockstep stall, stores from early waves
// overlap fragment loads of late waves. Interleaved epilogue retained
// (verified neutral); plain stores (nt verified -8 us, rejected).
__global__ __launch_bounds__(256) void gauss_mfma_kernel(
        const float* __restrict__ ws, float* __restrict__ out) {
    const int b = blockIdx.z;
    const int n0 = blockIdx.y * 128, m0 = blockIdx.x * 128;
    const int t = threadIdx.x;
    const int lane = t & 63;
    const int w = t >> 6;
    const int wn = (w & 1) * 64, wm = (w >> 1) * 64;
    const int mrow = lane & 15;
    const int quad = lane >> 4;

    const unsigned short* embT = (const unsigned short*)(ws + EMBT_OFF);

    // direct global fragment loads: row r's 64 bf16 = 128 B; this lane takes
    // bytes [ (ks*4+quad)*16 , +16 ) of rows {base + i*16 + mrow}
    bf16x8 af[2][4], bv[2][4];
#pragma unroll
    for (int ks = 0; ks < 2; ++ks) {
#pragma unroll
        for (int i = 0; i < 4; ++i) {
            const int ra = n0 + wn + i * 16 + mrow;
            af[ks][i] = *(const bf16x8*)(embT
                    + (((size_t)(b * NDIM + ra)) << 6) + (ks * 4 + quad) * 8);
            const int rb = m0 + wm + i * 16 + mrow;
            bv[ks][i] = *(const bf16x8*)(embT
                    + (((size_t)(b * NDIM + rb)) << 6) + (ks * 4 + quad) * 8);
        }
    }

    // wave-local reduction of the 256 prep partials (coalesced 256B loads,
    // butterfly leaves S,Q in every lane)
    float S = ws[PSUM_OFF + lane]       + ws[PSUM_OFF + 64 + lane]
            + ws[PSUM_OFF + 128 + lane] + ws[PSUM_OFF + 192 + lane];
    float Q = ws[PSQ_OFF + lane]        + ws[PSQ_OFF + 64 + lane]
            + ws[PSQ_OFF + 128 + lane]  + ws[PSQ_OFF + 192 + lane];
#pragma unroll
    for (int off = 32; off > 0; off >>= 1) {
        S += __shfl_xor(S, off, 64);
        Q += __shfl_xor(Q, off, 64);
    }

    const float M = (float)MTOT;
    const float var = (Q - S * S / M) / (M - 1.0f);
    const float sc = LOG2E / (var * (float)FDIM * SIGMA);   // log2e folded in
    const float s2 = 2.0f * sc;

    // per-row/-col bias terms straight from the L2-hot colsq array
    const float* colsq = ws + (size_t)b * NDIM;
    f32x4 qm4[4];
    float qnt[4];
#pragma unroll
    for (int j = 0; j < 4; ++j)
        qm4[j] = *(const f32x4*)&colsq[m0 + wm + j * 16 + quad * 4];
#pragma unroll
    for (int i = 0; i < 4; ++i)
        qnt[i] = -sc * colsq[n0 + wn + i * 16 + mrow];

    const size_t obase = (size_t)b * NDIM * NDIM;
#pragma unroll
    for (int i = 0; i < 4; ++i) {
        const int n = wn + i * 16 + mrow;                 // n index (lane&15 side)
#pragma unroll
        for (int j = 0; j < 4; ++j) {
            const int mbase = wm + j * 16 + quad * 4;     // m index (reg side)
            f32x4 acc = {};
            // swapped: D rows <- bv (m side), D cols <- af (n side)
            acc = __builtin_amdgcn_mfma_f32_16x16x32_bf16(bv[0][j], af[0][i], acc, 0, 0, 0);
            acc = __builtin_amdgcn_mfma_f32_16x16x32_bf16(bv[1][j], af[1][i], acc, 0, 0, 0);
            f32x4 o;
            o[0] = exp2f(fmaf(s2, acc[0], fmaf(-sc, qm4[j][0], qnt[i])));
            o[1] = exp2f(fmaf(s2, acc[1], fmaf(-sc, qm4[j][1], qnt[i])));
            o[2] = exp2f(fmaf(s2, acc[2], fmaf(-sc, qm4[j][2], qnt[i])));
            o[3] = exp2f(fmaf(s2, acc[3], fmaf(-sc, qm4[j][3], qnt[i])));
            *(f32x4*)&out[obase + (size_t)(n0 + n) * NDIM + (m0 + mbase)] = o;
        }
    }
}

extern "C" void kernel_launch(void* const* d_in, const int* in_sizes, int n_in,
                              void* d_out, int out_size, void* d_ws, size_t ws_size,
                              hipStream_t stream) {
    // d_in[0] = adj_in (unused by reference). d_in[1] = emb_in [8,64,2048] fp32.
    const float* emb = (const float*)d_in[1];
    float* out = (float*)d_out;
    float* ws  = (float*)d_ws;

    prep_kernel<<<NPREP, 64, 0, stream>>>(emb, ws);

    dim3 grid(NDIM / 128, NDIM / 128, BATCH);
    gauss_mfma_kernel<<<grid, 256, 0, stream>>>(ws, out);
}

// Round 8
// 210.428 us; speedup vs baseline: 1.0669x; 1.0669x over previous
//
#include <hip/hip_runtime.h>
#include <math.h>

#define BATCH 8
#define FDIM  64
#define NDIM  2048
#define MTOT  (BATCH * FDIM * NDIM)
#define SIGMA 2.0f
#define LOG2E 1.4426950408889634f

#define COLSQ_N (BATCH * NDIM)             // 16384 colsq floats
#define NPREP   256                        // prep block count
#define PSUM_OFF (COLSQ_N)                 // 256 per-block sums
#define PSQ_OFF  (COLSQ_N + NPREP)         // 256 per-block sumsqs
#define EMBT_OFF (COLSQ_N + 2 * NPREP)     // bf16 embT starts (byte 67584, 64B aligned)

typedef __attribute__((ext_vector_type(8))) short bf16x8;
typedef __attribute__((ext_vector_type(4))) float f32x4;

static __device__ inline unsigned short f2bf(float x) {
    unsigned int u = __float_as_uint(x);
    return (unsigned short)((u + 0x7fffu + ((u >> 16) & 1u)) >> 16);   // RTNE
}

// prep: 256 blocks x 1 wave, one column per thread. Produces:
//   colsq[b*NDIM+n], per-block partial (sum,sumsq) — no atomics, no memset —
//   and bf16 embT[b][n][f] for 16B-coalesced GEMM staging.
__global__ __launch_bounds__(64) void prep_kernel(
        const float* __restrict__ emb, float* __restrict__ ws) {
    const int blk = blockIdx.x;
    const int b = blk >> 5;
    const int n = ((blk & 31) << 6) + threadIdx.x;
    const float* p = emb + (size_t)b * FDIM * NDIM + n;
    unsigned short* dst = (unsigned short*)(ws + EMBT_OFF) + (size_t)(b * NDIM + n) * FDIM;

    float s = 0.f, q = 0.f;
#pragma unroll
    for (int f0 = 0; f0 < FDIM; f0 += 8) {
        unsigned int wv[4];
#pragma unroll
        for (int j = 0; j < 4; ++j) {
            float a = p[(size_t)(f0 + 2 * j) * NDIM];
            float c = p[(size_t)(f0 + 2 * j + 1) * NDIM];
            s += a + c;
            q += a * a + c * c;
            wv[j] = (unsigned)f2bf(a) | ((unsigned)f2bf(c) << 16);
        }
        *(uint4*)(dst + f0) = make_uint4(wv[0], wv[1], wv[2], wv[3]);
    }
    ws[b * NDIM + n] = q;

#pragma unroll
    for (int off = 32; off > 0; off >>= 1) {
        s += __shfl_down(s, off, 64);
        q += __shfl_down(q, off, 64);
    }
    if (threadIdx.x == 0) {
        ws[PSUM_OFF + blk] = s;
        ws[PSQ_OFF + blk] = q;
    }
}

// gauss (R8): R6 base (LDS-staged operands, fragments up-front, interleaved
// MFMA+exp) + LDS-TRANSPOSE EPILOGUE. Theory: the raw C/D-layout store emits
// 16x64B scattered segments per instruction; if TCC dirty-tracking is
// 128B-line (not 64B-sector), each partial-line store RMW-fetches poisoned
// output from HBM -> gauss traffic doubles (134MB rd + 134MB wr = 41us at
// 6.6TB/s = exactly the observed residual). Fix: per-wave 4KB LDS scratch
// (overlaid on At after fragments are in regs) turns each store into
// 256B-contiguous 16-lane segments = guaranteed full-line writes.
__global__ __launch_bounds__(256) void gauss_mfma_kernel(
        const float* __restrict__ ws, float* __restrict__ out) {
    // manual LDS layout so the epilogue scratch can overlay At
    __shared__ __align__(16) unsigned char smem[128 * 64 * 2 * 2 + 256 * 4 + 8 * 4];
    unsigned short* At = (unsigned short*)smem;                 // 16 KB
    unsigned short* Bt = At + 128 * 64;                         // 16 KB
    float* qs  = (float*)(Bt + 128 * 64);                       // 1 KB
    float* red = qs + 256;                                      // 32 B
    float* epi = (float*)smem;                                  // overlay on At (16 KB)

    const int b = blockIdx.z;
    const int n0 = blockIdx.y * 128, m0 = blockIdx.x * 128;
    const int t = threadIdx.x;
    const unsigned short* embT = (const unsigned short*)(ws + EMBT_OFF);
    const unsigned short* baseA = embT + (size_t)(b * NDIM + n0) * FDIM;
    const unsigned short* baseB = embT + (size_t)(b * NDIM + m0) * FDIM;

    // in-block reduction of prep partials
    {
        float s = ws[PSUM_OFF + t];
        float q = ws[PSQ_OFF + t];
#pragma unroll
        for (int off = 32; off > 0; off >>= 1) {
            s += __shfl_down(s, off, 64);
            q += __shfl_down(q, off, 64);
        }
        if ((t & 63) == 0) { red[t >> 6] = s; red[4 + (t >> 6)] = q; }
    }

    // stage both tiles, XOR-swizzled LDS chunks (conflict-free b128 reads)
    {
        const int row = t >> 3, c = t & 7;
#pragma unroll
        for (int it = 0; it < 4; ++it) {
            int r = row + it * 32;
            int slot = c ^ (r & 7);
            *(float4*)&At[r * 64 + slot * 8] = *(const float4*)(baseA + r * 64 + c * 8);
            *(float4*)&Bt[r * 64 + slot * 8] = *(const float4*)(baseB + r * 64 + c * 8);
        }
        qs[t] = (t < 128) ? ws[b * NDIM + n0 + t] : ws[b * NDIM + m0 + (t - 128)];
    }
    __syncthreads();

    const int lane = t & 63;
    const int w = t >> 6;
    const int wn = (w & 1) * 64, wm = (w >> 1) * 64;
    const int mrow = lane & 15;
    const int quad = lane >> 4;

    // load all 16 fragments up front (after this, At/Bt content is dead)
    bf16x8 af[2][4], bv[2][4];
#pragma unroll
    for (int ks = 0; ks < 2; ++ks) {
#pragma unroll
        for (int i = 0; i < 4; ++i) {
            int ra = wn + i * 16 + mrow;
            int ca = (ks * 4 + quad) ^ (ra & 7);
            af[ks][i] = *(bf16x8*)&At[ra * 64 + ca * 8];
            int rb = wm + i * 16 + mrow;
            int cb = (ks * 4 + quad) ^ (rb & 7);
            bv[ks][i] = *(bf16x8*)&Bt[rb * 64 + cb * 8];
        }
    }

    // finish the global reduction redundantly per thread
    const float S = red[0] + red[1] + red[2] + red[3];
    const float Q = red[4] + red[5] + red[6] + red[7];
    const float M = (float)MTOT;
    const float var = (Q - S * S / M) / (M - 1.0f);
    const float sc = LOG2E / (var * (float)FDIM * SIGMA);   // log2e folded in
    const float s2 = 2.0f * sc;

    // per-row/-col bias terms (read qs before it could ever be overlaid)
    f32x4 qm4[4];
    float qnt[4];
#pragma unroll
    for (int j = 0; j < 4; ++j)
        qm4[j] = *(f32x4*)&qs[128 + wm + j * 16 + quad * 4];
#pragma unroll
    for (int i = 0; i < 4; ++i)
        qnt[i] = -sc * qs[wn + i * 16 + mrow];

    // all waves done reading At -> safe to overlay epilogue scratch on it
    __syncthreads();

    float* myepi = epi + w * 1024;   // 4 KB per wave, 16 rows x 64 f32
    const size_t obase = (size_t)b * NDIM * NDIM;

#pragma unroll
    for (int i = 0; i < 4; ++i) {
        // compute + LDS-write this wave's 16x64 f32 tile (swizzled 16B slots)
#pragma unroll
        for (int j = 0; j < 4; ++j) {
            f32x4 acc = {};
            // swapped: D rows <- bv (m side), D cols <- af (n side)
            acc = __builtin_amdgcn_mfma_f32_16x16x32_bf16(bv[0][j], af[0][i], acc, 0, 0, 0);
            acc = __builtin_amdgcn_mfma_f32_16x16x32_bf16(bv[1][j], af[1][i], acc, 0, 0, 0);
            f32x4 o;
            o[0] = exp2f(fmaf(s2, acc[0], fmaf(-sc, qm4[j][0], qnt[i])));
            o[1] = exp2f(fmaf(s2, acc[1], fmaf(-sc, qm4[j][1], qnt[i])));
            o[2] = exp2f(fmaf(s2, acc[2], fmaf(-sc, qm4[j][2], qnt[i])));
            o[3] = exp2f(fmaf(s2, acc[3], fmaf(-sc, qm4[j][3], qnt[i])));
            // logical slot (16B) = j*4+quad in row mrow; XOR-swizzle by row
            const int ps = (j * 4 + quad) ^ (mrow & 7);
            *(f32x4*)&myepi[mrow * 64 + ps * 4] = o;
        }
        // read back transposed: lane (quad=row-group, mrow=col-chunk) ->
        // 16-lane groups store 256B contiguous = full 128B lines, no RMW
#pragma unroll
        for (int ri = 0; ri < 4; ++ri) {
            const int row = quad + ri * 4;                  // 0..15 within tile
            const int ps = mrow ^ (row & 7);
            f32x4 v = *(f32x4*)&myepi[row * 64 + ps * 4];
            const int n = wn + i * 16 + row;                // output row (n axis)
            *(f32x4*)&out[obase + (size_t)(n0 + n) * NDIM + (m0 + wm + mrow * 4)] = v;
        }
    }
}

extern "C" void kernel_launch(void* const* d_in, const int* in_sizes, int n_in,
                              void* d_out, int out_size, void* d_ws, size_t ws_size,
                              hipStream_t stream) {
    // d_in[0] = adj_in (unused by reference). d_in[1] = emb_in [8,64,2048] fp32.
    const float* emb = (const float*)d_in[1];
    float* out = (float*)d_out;
    float* ws  = (float*)d_ws;

    prep_kernel<<<NPREP, 64, 0, stream>>>(emb, ws);

    dim3 grid(NDIM / 128, NDIM / 128, BATCH);
    gauss_mfma_kernel<<<grid, 256, 0, stream>>>(ws, out);
}